// Round 9
// baseline (274.246 us; speedup 1.0000x reference)
//
#include <hip/hip_runtime.h>

#define FF 128
#define BCAP 8192       // per-bucket region capacity (avg ~4081 for seeded input)
#define CHUNK 4096      // edges per partA block

typedef __attribute__((ext_vector_type(8))) short short8;
typedef __attribute__((ext_vector_type(4))) float f32x4;

__device__ __forceinline__ unsigned short bf16_rne(float f) {
    unsigned u = __float_as_uint(f);
    u += 0x7fffu + ((u >> 16) & 1u);
    return (unsigned short)(u >> 16);
}
__device__ __forceinline__ float bf16_to_f32(unsigned short h) {
    return __uint_as_float(((unsigned)h) << 16);
}

// ---------------------------------------------------------------------------
// Pool matmul (PRE=L2-normalize, fp32 in, bf16 h + bf16 h^2 out).
// W in FRAGMENT-MAJOR bf16 hi/lo planes (wave frag = coalesced 1KB dwordx4).
// 64-node tile, 4 waves; CT col-tiles per wave. 3-term A split.
// ---------------------------------------------------------------------------
template<int OUT, int PRE, int ADD, int RELU, int ABF16, int OUTBF16, int OUTSQ>
__global__ __launch_bounds__(256, 2)
void mm_mfma(const void* __restrict__ xin_,
             const unsigned short* __restrict__ Wh, const unsigned short* __restrict__ Wl,
             const float* __restrict__ bias, const float* __restrict__ addsrc,
             void* __restrict__ out_, unsigned short* __restrict__ hsq_out, int N)
{
    constexpr int PITCH = 136;
    __shared__ unsigned short sXh[64 * PITCH];
    __shared__ unsigned short sXl[ABF16 ? 1 : 64 * PITCH];

    const int tid  = threadIdx.x;
    const int tile = blockIdx.x;

    #pragma unroll
    for (int rg = 0; rg < 2; ++rg) {
        const int row = rg * 32 + (tid >> 3);
        const int c0  = (tid & 7) * 16;
        const int n   = tile * 64 + row;
        const int base = row * PITCH + c0;
        if constexpr (ABF16) {
            const unsigned short* xin = (const unsigned short*)xin_;
            short8 a = {0,0,0,0,0,0,0,0}, b = a;
            if (n < N) {
                const short8* p = (const short8*)(xin + (size_t)n * FF + c0);
                a = p[0]; b = p[1];
            }
            *(short8*)&sXh[base]     = a;
            *(short8*)&sXh[base + 8] = b;
        } else {
            const float* xin = (const float*)xin_;
            float v[16];
            if (n < N) {
                const float4* p = (const float4*)(xin + (size_t)n * FF + c0);
                #pragma unroll
                for (int i = 0; i < 4; ++i) {
                    float4 q = p[i];
                    v[4*i] = q.x; v[4*i+1] = q.y; v[4*i+2] = q.z; v[4*i+3] = q.w;
                }
            } else {
                #pragma unroll
                for (int i = 0; i < 16; ++i) v[i] = 0.f;
            }
            if constexpr (PRE == 1) {
                float ss = 0.f;
                #pragma unroll
                for (int i = 0; i < 16; ++i) ss = fmaf(v[i], v[i], ss);
                ss += __shfl_xor(ss, 1);
                ss += __shfl_xor(ss, 2);
                ss += __shfl_xor(ss, 4);
                float scl = 1.0f / fmaxf(sqrtf(ss), 1e-12f);
                #pragma unroll
                for (int i = 0; i < 16; ++i) v[i] *= scl;
            }
            union { unsigned short u[8]; short8 s; } h0, h1, l0, l1;
            #pragma unroll
            for (int i = 0; i < 8; ++i) {
                unsigned short ha = bf16_rne(v[i]);
                unsigned short hb = bf16_rne(v[8 + i]);
                h0.u[i] = ha; h1.u[i] = hb;
                l0.u[i] = bf16_rne(v[i]     - bf16_to_f32(ha));
                l1.u[i] = bf16_rne(v[8 + i] - bf16_to_f32(hb));
            }
            *(short8*)&sXh[base]     = h0.s;
            *(short8*)&sXh[base + 8] = h1.s;
            *(short8*)&sXl[base]     = l0.s;
            *(short8*)&sXl[base + 8] = l1.s;
        }
    }
    __syncthreads();

    const int lane = tid & 63, wave = tid >> 6;
    const int quad = lane >> 4, l16 = lane & 15;
    constexpr int CT = (OUT == 128) ? 2 : 1;

    short8 Bh[CT][4], Bl[CT][4];
    #pragma unroll
    for (int c = 0; c < CT; ++c) {
        const int jt = (OUT == 128) ? (2 * wave + c) : wave;
        #pragma unroll
        for (int t = 0; t < 4; ++t) {
            const size_t o = ((size_t)(jt * 4 + t) * 64 + lane) * 8;
            Bh[c][t] = *(const short8*)&Wh[o];
            Bl[c][t] = *(const short8*)&Wl[o];
        }
    }

    f32x4 acc[4][CT];
    #pragma unroll
    for (int r = 0; r < 4; ++r)
        #pragma unroll
        for (int c = 0; c < CT; ++c) {
            f32x4 z = {0.f, 0.f, 0.f, 0.f};
            acc[r][c] = z;
        }

    #pragma unroll
    for (int t = 0; t < 4; ++t) {
        short8 Ah[4], Al[4];
        #pragma unroll
        for (int r = 0; r < 4; ++r) {
            const int off = (r * 16 + l16) * PITCH + t * 32 + quad * 8;
            Ah[r] = *(const short8*)&sXh[off];
            if constexpr (!ABF16) Al[r] = *(const short8*)&sXl[off];
        }
        #pragma unroll
        for (int c = 0; c < CT; ++c)
            #pragma unroll
            for (int r = 0; r < 4; ++r) {
                acc[r][c] = __builtin_amdgcn_mfma_f32_16x16x32_bf16(Ah[r], Bh[c][t], acc[r][c], 0, 0, 0);
                if constexpr (!ABF16)
                    acc[r][c] = __builtin_amdgcn_mfma_f32_16x16x32_bf16(Al[r], Bh[c][t], acc[r][c], 0, 0, 0);
                acc[r][c] = __builtin_amdgcn_mfma_f32_16x16x32_bf16(Ah[r], Bl[c][t], acc[r][c], 0, 0, 0);
            }
    }

    #pragma unroll
    for (int c = 0; c < CT; ++c) {
        const int jt = (OUT == 128) ? (2 * wave + c) : wave;
        const int j = jt * 16 + l16;
        const float bj = bias[j];
        #pragma unroll
        for (int r = 0; r < 4; ++r) {
            #pragma unroll
            for (int g = 0; g < 4; ++g) {
                const int n = tile * 64 + r * 16 + quad * 4 + g;
                if (n < N) {
                    float val = acc[r][c][g] + bj;
                    if constexpr (ADD) val += addsrc[(size_t)n * OUT + j];
                    if constexpr (RELU) val = fmaxf(val, 0.f);
                    if constexpr (OUTBF16)
                        ((unsigned short*)out_)[(size_t)n * OUT + j] = bf16_rne(val);
                    else
                        ((float*)out_)[(size_t)n * OUT + j] = val;
                    if constexpr (OUTSQ)
                        hsq_out[(size_t)n * OUT + j] = bf16_rne(val * val);
                }
            }
        }
    }
}

// ---------------------------------------------------------------------------
// Fused fc1+fc2: out[n][j] = act( h[n]@W1[j] + agg[n]@W2[j] + b1[j]+b2[j] )
// h bf16 (exact, 2-term); agg given as precomputed bf16 hi/lo planes (3-term)
// -> staging is pure copies, no per-element split math.
// ---------------------------------------------------------------------------
template<int OUT, int RELU>
__global__ __launch_bounds__(256, 2)
void mm2_mfma(const unsigned short* __restrict__ hin,
              const unsigned short* __restrict__ aggh, const unsigned short* __restrict__ aggl,
              const unsigned short* __restrict__ W1h, const unsigned short* __restrict__ W1l,
              const unsigned short* __restrict__ W2h, const unsigned short* __restrict__ W2l,
              const float* __restrict__ b1, const float* __restrict__ b2,
              float* __restrict__ out_, int N)
{
    constexpr int PITCH = 136;
    __shared__ unsigned short sH [64 * PITCH];
    __shared__ unsigned short sAh[64 * PITCH];
    __shared__ unsigned short sAl[64 * PITCH];

    const int tid  = threadIdx.x;
    const int tile = blockIdx.x;

    #pragma unroll
    for (int rg = 0; rg < 2; ++rg) {
        const int row = rg * 32 + (tid >> 3);
        const int c0  = (tid & 7) * 16;
        const int n   = tile * 64 + row;
        const int base = row * PITCH + c0;
        short8 z = {0,0,0,0,0,0,0,0};
        short8 a = z, b = z, c = z, d = z, e = z, f = z;
        if (n < N) {
            const short8* ph = (const short8*)(hin  + (size_t)n * FF + c0);
            const short8* pa = (const short8*)(aggh + (size_t)n * FF + c0);
            const short8* pl = (const short8*)(aggl + (size_t)n * FF + c0);
            a = ph[0]; b = ph[1];
            c = pa[0]; d = pa[1];
            e = pl[0]; f = pl[1];
        }
        *(short8*)&sH [base]     = a;
        *(short8*)&sH [base + 8] = b;
        *(short8*)&sAh[base]     = c;
        *(short8*)&sAh[base + 8] = d;
        *(short8*)&sAl[base]     = e;
        *(short8*)&sAl[base + 8] = f;
    }
    __syncthreads();

    const int lane = tid & 63, wave = tid >> 6;
    const int quad = lane >> 4, l16 = lane & 15;
    constexpr int CT = (OUT == 128) ? 2 : 1;

    short8 B1hf[CT][4], B1lf[CT][4], B2hf[CT][4], B2lf[CT][4];
    #pragma unroll
    for (int c = 0; c < CT; ++c) {
        const int jt = (OUT == 128) ? (2 * wave + c) : wave;
        #pragma unroll
        for (int t = 0; t < 4; ++t) {
            const size_t o = ((size_t)(jt * 4 + t) * 64 + lane) * 8;
            B1hf[c][t] = *(const short8*)&W1h[o];
            B1lf[c][t] = *(const short8*)&W1l[o];
            B2hf[c][t] = *(const short8*)&W2h[o];
            B2lf[c][t] = *(const short8*)&W2l[o];
        }
    }

    f32x4 acc[4][CT];
    #pragma unroll
    for (int r = 0; r < 4; ++r)
        #pragma unroll
        for (int c = 0; c < CT; ++c) {
            f32x4 z = {0.f, 0.f, 0.f, 0.f};
            acc[r][c] = z;
        }

    #pragma unroll
    for (int t = 0; t < 4; ++t) {
        short8 Hf[4], AH[4], AL[4];
        #pragma unroll
        for (int r = 0; r < 4; ++r) {
            const int off = (r * 16 + l16) * PITCH + t * 32 + quad * 8;
            Hf[r] = *(const short8*)&sH[off];
            AH[r] = *(const short8*)&sAh[off];
            AL[r] = *(const short8*)&sAl[off];
        }
        #pragma unroll
        for (int c = 0; c < CT; ++c)
            #pragma unroll
            for (int r = 0; r < 4; ++r) {
                acc[r][c] = __builtin_amdgcn_mfma_f32_16x16x32_bf16(Hf[r], B1hf[c][t], acc[r][c], 0, 0, 0);
                acc[r][c] = __builtin_amdgcn_mfma_f32_16x16x32_bf16(Hf[r], B1lf[c][t], acc[r][c], 0, 0, 0);
                acc[r][c] = __builtin_amdgcn_mfma_f32_16x16x32_bf16(AH[r], B2hf[c][t], acc[r][c], 0, 0, 0);
                acc[r][c] = __builtin_amdgcn_mfma_f32_16x16x32_bf16(AL[r], B2hf[c][t], acc[r][c], 0, 0, 0);
                acc[r][c] = __builtin_amdgcn_mfma_f32_16x16x32_bf16(AH[r], B2lf[c][t], acc[r][c], 0, 0, 0);
            }
    }

    #pragma unroll
    for (int c = 0; c < CT; ++c) {
        const int jt = (OUT == 128) ? (2 * wave + c) : wave;
        const int j = jt * 16 + l16;
        const float bj = b1[j] + b2[j];
        #pragma unroll
        for (int r = 0; r < 4; ++r) {
            #pragma unroll
            for (int g = 0; g < 4; ++g) {
                const int n = tile * 64 + r * 16 + quad * 4 + g;
                if (n < N) {
                    float val = acc[r][c][g] + bj;
                    if constexpr (RELU) val = fmaxf(val, 0.f);
                    out_[(size_t)n * OUT + j] = val;
                }
            }
        }
    }
}

// ---------------------------------------------------------------------------
// Weight prep: fp32 [OUT][128] -> fragment-major bf16 hi/lo planes.
// ---------------------------------------------------------------------------
struct WPack {
    const float* src[6];
    unsigned short* hi[6];
    unsigned short* lo[6];
    int n[6];
};

__global__ __launch_bounds__(256)
void wprep_kernel(WPack p)
{
    int id = blockIdx.x * 256 + threadIdx.x;
    #pragma unroll
    for (int i = 0; i < 6; ++i) {
        if (id < p.n[i]) {
            float f = p.src[i][id];
            unsigned short h = bf16_rne(f);
            const int j = id >> 7, k = id & 127;
            const int jt = j >> 4, l16 = j & 15;
            const int t = k >> 5, quad = (k >> 3) & 3, j8 = k & 7;
            const size_t o = ((size_t)((jt * 4 + t) * 4 + quad) * 16 + l16) * 8 + j8;
            p.hi[i][o] = h;
            p.lo[i][o] = bf16_rne(f - bf16_to_f32(h));
            return;
        }
        id -= p.n[i];
    }
}

// ---------------------------------------------------------------------------
// Pass A: bucket partition. bucket = dst >> 8. Edges staged in LDS grouped by
// bucket, then written as coalesced runs into over-provisioned bucket regions.
// Entry: {x = src | (dst<<16), y = val fp32}.   (requires N <= 65536)
// ---------------------------------------------------------------------------
__global__ __launch_bounds__(256)
void partA_kernel(const int* __restrict__ src, const int* __restrict__ dst,
                  const float* __restrict__ val, int* __restrict__ bucket_cnt,
                  int2* __restrict__ ebuf, int E)
{
    __shared__ int cnt[256], sc[256], excl[256], cur[256], gbase[256];
    __shared__ int2 staged[CHUNK];
    const int t = threadIdx.x;
    const int e0 = blockIdx.x * CHUNK;
    const int n  = min(CHUNK, E - e0);

    cnt[t] = 0;
    __syncthreads();
    for (int i = t; i < n; i += 256)
        atomicAdd(&cnt[((unsigned)dst[e0 + i]) >> 8], 1);
    __syncthreads();

    sc[t] = cnt[t];
    __syncthreads();
    #pragma unroll
    for (int off = 1; off < 256; off <<= 1) {
        int v = (t >= off) ? sc[t - off] : 0;
        __syncthreads();
        sc[t] += v;
        __syncthreads();
    }
    excl[t] = sc[t] - cnt[t];
    cur[t]  = excl[t];
    if (cnt[t] > 0) gbase[t] = atomicAdd(&bucket_cnt[t], cnt[t]);
    __syncthreads();

    for (int i = t; i < n; i += 256) {
        int d = dst[e0 + i];
        int s = src[e0 + i];
        float v = val[e0 + i];
        int b = ((unsigned)d) >> 8;
        int slot = atomicAdd(&cur[b], 1);
        staged[slot] = make_int2((s & 0xffff) | (d << 16), __float_as_int(v));
    }
    __syncthreads();

    for (int p = t; p < n; p += 256) {
        int2 ent = staged[p];
        int b = ((unsigned)ent.x) >> 24;
        int gpos = gbase[b] + (p - excl[b]);
        ebuf[(size_t)b * BCAP + gpos] = ent;
    }
}

// ---------------------------------------------------------------------------
// Pass B: per-bucket fine sort. One block per bucket. Computes per-dst offsets,
// then scatters final edata {src, val} into the bucket's compact region.
// ---------------------------------------------------------------------------
__global__ __launch_bounds__(256)
void partB_kernel(const int* __restrict__ bucket_cnt, const int2* __restrict__ ebuf,
                  int* __restrict__ offsets, int2* __restrict__ edata,
                  int N, int E, int nbuck)
{
    __shared__ int pre[256], hist[256], sc[256], excl[256], cur[256];
    const int t = threadIdx.x;
    const int b = blockIdx.x;

    pre[t] = (t < nbuck) ? bucket_cnt[t] : 0;
    __syncthreads();
    #pragma unroll
    for (int off = 1; off < 256; off <<= 1) {
        int v = (t >= off) ? pre[t - off] : 0;
        __syncthreads();
        pre[t] += v;
        __syncthreads();
    }
    const int base = (b == 0) ? 0 : pre[b - 1];
    const int cnt  = pre[b] - base;

    hist[t] = 0;
    __syncthreads();
    const int2* ib = ebuf + (size_t)b * BCAP;
    for (int i = t; i < cnt; i += 256)
        atomicAdd(&hist[(((unsigned)ib[i].x) >> 16) & 255], 1);
    __syncthreads();

    sc[t] = hist[t];
    __syncthreads();
    #pragma unroll
    for (int off = 1; off < 256; off <<= 1) {
        int v = (t >= off) ? sc[t - off] : 0;
        __syncthreads();
        sc[t] += v;
        __syncthreads();
    }
    excl[t] = sc[t] - hist[t];
    cur[t]  = excl[t];

    const int node = b * 256 + t;
    if (node <= N) offsets[node] = base + excl[t];
    __syncthreads();

    for (int i = t; i < cnt; i += 256) {
        int2 ent = ib[i];
        int l = (((unsigned)ent.x) >> 16) & 255;
        int pos = base + atomicAdd(&cur[l], 1);
        edata[pos] = make_int2(ent.x & 0xffff, ent.y);
    }
}

// ---------------------------------------------------------------------------
// CSR aggregation over bf16 hsq: one node per 32-lane group (8 nodes/block);
// lane covers 4 feats (one 8B read). 8-deep unroll: 4 int4 edata loads +
// 8 row gathers in flight. Writes agg = sqrt(sum) as bf16 hi/lo planes.
// ---------------------------------------------------------------------------
__device__ __forceinline__ void fma4(float4& a, float v, uint2 u) {
    a.x = fmaf(v, __uint_as_float(u.x << 16), a.x);
    a.y = fmaf(v, __uint_as_float(u.x & 0xffff0000u), a.y);
    a.z = fmaf(v, __uint_as_float(u.y << 16), a.z);
    a.w = fmaf(v, __uint_as_float(u.y & 0xffff0000u), a.w);
}

__global__ __launch_bounds__(256)
void agg_kernel(const unsigned short* __restrict__ hsq, const int* __restrict__ offsets,
                const int2* __restrict__ edata,
                unsigned short* __restrict__ aggh, unsigned short* __restrict__ aggl, int N)
{
    const int w = blockIdx.x * 8 + (threadIdx.x >> 5);
    if (w >= N) return;
    const int l = threadIdx.x & 31;
    const size_t fo = (size_t)(l * 4);
    int e = offsets[w];
    const int end = offsets[w + 1];

    float4 a0 = {0,0,0,0}, a1 = {0,0,0,0}, a2 = {0,0,0,0}, a3 = {0,0,0,0};
    float4 a4 = {0,0,0,0}, a5 = {0,0,0,0}, a6 = {0,0,0,0}, a7 = {0,0,0,0};

    if ((e & 1) && e < end) {
        int2 ed = edata[e];
        uint2 u = *(const uint2*)&hsq[(size_t)ed.x * FF + fo];
        fma4(a0, __int_as_float(ed.y), u);
        ++e;
    }
    for (; e + 7 < end; e += 8) {
        int4 p0 = *(const int4*)&edata[e];
        int4 p1 = *(const int4*)&edata[e + 2];
        int4 p2 = *(const int4*)&edata[e + 4];
        int4 p3 = *(const int4*)&edata[e + 6];
        uint2 u0 = *(const uint2*)&hsq[(size_t)p0.x * FF + fo];
        uint2 u1 = *(const uint2*)&hsq[(size_t)p0.z * FF + fo];
        uint2 u2 = *(const uint2*)&hsq[(size_t)p1.x * FF + fo];
        uint2 u3 = *(const uint2*)&hsq[(size_t)p1.z * FF + fo];
        uint2 u4 = *(const uint2*)&hsq[(size_t)p2.x * FF + fo];
        uint2 u5 = *(const uint2*)&hsq[(size_t)p2.z * FF + fo];
        uint2 u6 = *(const uint2*)&hsq[(size_t)p3.x * FF + fo];
        uint2 u7 = *(const uint2*)&hsq[(size_t)p3.z * FF + fo];
        fma4(a0, __int_as_float(p0.y), u0);
        fma4(a1, __int_as_float(p0.w), u1);
        fma4(a2, __int_as_float(p1.y), u2);
        fma4(a3, __int_as_float(p1.w), u3);
        fma4(a4, __int_as_float(p2.y), u4);
        fma4(a5, __int_as_float(p2.w), u5);
        fma4(a6, __int_as_float(p3.y), u6);
        fma4(a7, __int_as_float(p3.w), u7);
    }
    for (; e + 3 < end; e += 4) {
        int4 p0 = *(const int4*)&edata[e];
        int4 p1 = *(const int4*)&edata[e + 2];
        uint2 u0 = *(const uint2*)&hsq[(size_t)p0.x * FF + fo];
        uint2 u1 = *(const uint2*)&hsq[(size_t)p0.z * FF + fo];
        uint2 u2 = *(const uint2*)&hsq[(size_t)p1.x * FF + fo];
        uint2 u3 = *(const uint2*)&hsq[(size_t)p1.z * FF + fo];
        fma4(a0, __int_as_float(p0.y), u0);
        fma4(a1, __int_as_float(p0.w), u1);
        fma4(a2, __int_as_float(p1.y), u2);
        fma4(a3, __int_as_float(p1.w), u3);
    }
    if (e + 1 < end) {
        int4 p = *(const int4*)&edata[e];
        uint2 u0 = *(const uint2*)&hsq[(size_t)p.x * FF + fo];
        uint2 u1 = *(const uint2*)&hsq[(size_t)p.z * FF + fo];
        fma4(a0, __int_as_float(p.y), u0);
        fma4(a1, __int_as_float(p.w), u1);
        e += 2;
    }
    if (e < end) {
        int2 ed = edata[e];
        uint2 u = *(const uint2*)&hsq[(size_t)ed.x * FF + fo];
        fma4(a0, __int_as_float(ed.y), u);
    }

    float4 r;
    r.x = sqrtf(a0.x + a1.x + a2.x + a3.x + a4.x + a5.x + a6.x + a7.x);
    r.y = sqrtf(a0.y + a1.y + a2.y + a3.y + a4.y + a5.y + a6.y + a7.y);
    r.z = sqrtf(a0.z + a1.z + a2.z + a3.z + a4.z + a5.z + a6.z + a7.z);
    r.w = sqrtf(a0.w + a1.w + a2.w + a3.w + a4.w + a5.w + a6.w + a7.w);

    unsigned short hx = bf16_rne(r.x), hy = bf16_rne(r.y);
    unsigned short hz = bf16_rne(r.z), hw = bf16_rne(r.w);
    unsigned short lx = bf16_rne(r.x - bf16_to_f32(hx));
    unsigned short ly = bf16_rne(r.y - bf16_to_f32(hy));
    unsigned short lz = bf16_rne(r.z - bf16_to_f32(hz));
    unsigned short lw = bf16_rne(r.w - bf16_to_f32(hw));
    uint2 hv = { (unsigned)hx | ((unsigned)hy << 16), (unsigned)hz | ((unsigned)hw << 16) };
    uint2 lv = { (unsigned)lx | ((unsigned)ly << 16), (unsigned)lz | ((unsigned)lw << 16) };
    *(uint2*)&aggh[(size_t)w * FF + fo] = hv;
    *(uint2*)&aggl[(size_t)w * FF + fo] = lv;
}

// ---------------------------------------------------------------------------
extern "C" void kernel_launch(void* const* d_in, const int* in_sizes, int n_in,
                              void* d_out, int out_size, void* d_ws, size_t ws_size,
                              hipStream_t stream) {
    const float* x    = (const float*)d_in[0];
    const int*   esrc = (const int*)d_in[1];
    const int*   edst = (const int*)d_in[2];
    const float* eval = (const float*)d_in[3];
    const float* pw0  = (const float*)d_in[4];
    const float* pb0  = (const float*)d_in[5];
    const float* f1w0 = (const float*)d_in[6];
    const float* f1b0 = (const float*)d_in[7];
    const float* f2w0 = (const float*)d_in[8];
    const float* f2b0 = (const float*)d_in[9];
    const float* pw1  = (const float*)d_in[10];
    const float* pb1  = (const float*)d_in[11];
    const float* f1w1 = (const float*)d_in[12];
    const float* f1b1 = (const float*)d_in[13];
    const float* f2w1 = (const float*)d_in[14];
    const float* f2b1 = (const float*)d_in[15];
    float* out = (float*)d_out;

    const int N = in_sizes[0] / FF;     // 50000  (must be <= 65536 for 16-bit packing)
    const int E = in_sizes[1];          // 800000
    const int nbuck = (N + 255) / 256;  // 196

    char* ws = (char*)d_ws;
    const size_t rowsz = (size_t)N * FF * sizeof(float);          // 25.6 MB
    const size_t A = 256;
    size_t off = 0;
    unsigned short* h    = (unsigned short*)(ws + off); off += (rowsz / 2 + A - 1) / A * A;
    unsigned short* hsq  = (unsigned short*)(ws + off); off += (rowsz / 2 + A - 1) / A * A;
    unsigned short* aggh = (unsigned short*)(ws + off); off += (rowsz / 2 + A - 1) / A * A;
    unsigned short* aggl = (unsigned short*)(ws + off); off += (rowsz / 2 + A - 1) / A * A;
    float* x1  = (float*)(ws + off); off += rowsz;
    int* offsets = (int*)(ws + off); off += ((size_t)(N + 1) * 4 + A - 1) / A * A;
    int* bucket_cnt = (int*)(ws + off); off += (size_t)256 * 4;
    int2* ebuf  = (int2*)(ws + off); off += (size_t)nbuck * BCAP * 8;   // 12.8 MB
    int2* edata = (int2*)(ws + off); off += (size_t)E * 8;
    const int wsz[6] = {128 * FF, 128 * FF, 128 * FF, 128 * FF, 64 * FF, 64 * FF};
    unsigned short* whi[6];
    unsigned short* wlo[6];
    for (int i = 0; i < 6; ++i) {
        whi[i] = (unsigned short*)(ws + off); off += (size_t)wsz[i] * 2;
        wlo[i] = (unsigned short*)(ws + off); off += (size_t)wsz[i] * 2;
    }

    WPack pack;
    const float* wsrc[6] = {pw0, f1w0, f2w0, pw1, f1w1, f2w1};
    int wtotal = 0;
    for (int i = 0; i < 6; ++i) {
        pack.src[i] = wsrc[i]; pack.hi[i] = whi[i]; pack.lo[i] = wlo[i]; pack.n[i] = wsz[i];
        wtotal += wsz[i];
    }

    const int ntiles     = (N + 63) / 64;
    const int nodeblocks = (N + 7) / 8;
    dim3 B(256);

    // ---- weight prep (fragment-major bf16 split) ----
    wprep_kernel<<<(wtotal + 255) / 256, B, 0, stream>>>(pack);

    // ---- edge partition + dst-sort ----
    hipMemsetAsync(bucket_cnt, 0, 256 * 4, stream);
    partA_kernel<<<(E + CHUNK - 1) / CHUNK, B, 0, stream>>>(esrc, edst, eval, bucket_cnt, ebuf, E);
    partB_kernel<<<nbuck, B, 0, stream>>>(bucket_cnt, ebuf, offsets, edata, N, E, nbuck);

    // ---- layer 0 (128 -> 128, relu) ----
    mm_mfma<128, 1, 0, 1, 0, 1, 1><<<ntiles, B, 0, stream>>>(x, whi[0], wlo[0], pb0, nullptr, h, hsq, N);
    agg_kernel<<<nodeblocks, B, 0, stream>>>(hsq, offsets, edata, aggh, aggl, N);
    mm2_mfma<128, 1><<<ntiles, B, 0, stream>>>(h, aggh, aggl, whi[1], wlo[1], whi[2], wlo[2], f1b0, f2b0, x1, N);

    // ---- layer 1 (128 -> 64, no act) ----
    mm_mfma<128, 1, 0, 1, 0, 1, 1><<<ntiles, B, 0, stream>>>(x1, whi[3], wlo[3], pb1, nullptr, h, hsq, N);
    agg_kernel<<<nodeblocks, B, 0, stream>>>(hsq, offsets, edata, aggh, aggl, N);
    mm2_mfma<64, 0><<<ntiles, B, 0, stream>>>(h, aggh, aggl, whi[4], wlo[4], whi[5], wlo[5], f1b1, f2b1, out, N);
}

// Round 10
// 257.209 us; speedup vs baseline: 1.0662x; 1.0662x over previous
//
#include <hip/hip_runtime.h>

#define FF 128
#define BCAP 8192       // per-bucket region capacity (avg ~4081 for seeded input)
#define CHUNK 4096      // edges per partA block

typedef __attribute__((ext_vector_type(8))) short short8;
typedef __attribute__((ext_vector_type(4))) float f32x4;

__device__ __forceinline__ unsigned short bf16_rne(float f) {
    unsigned u = __float_as_uint(f);
    u += 0x7fffu + ((u >> 16) & 1u);
    return (unsigned short)(u >> 16);
}
__device__ __forceinline__ float bf16_to_f32(unsigned short h) {
    return __uint_as_float(((unsigned)h) << 16);
}

// ---------------------------------------------------------------------------
// Pool matmul (PRE=L2-normalize, fp32 in, bf16 h + bf16 h^2 out).
// W in FRAGMENT-MAJOR bf16 hi/lo planes (wave frag = coalesced 1KB dwordx4).
// 64-node tile, 4 waves; CT col-tiles per wave. 3-term A split.
// ---------------------------------------------------------------------------
template<int OUT, int PRE, int ADD, int RELU, int ABF16, int OUTBF16, int OUTSQ>
__global__ __launch_bounds__(256, 2)
void mm_mfma(const void* __restrict__ xin_,
             const unsigned short* __restrict__ Wh, const unsigned short* __restrict__ Wl,
             const float* __restrict__ bias, const float* __restrict__ addsrc,
             void* __restrict__ out_, unsigned short* __restrict__ hsq_out, int N)
{
    constexpr int PITCH = 136;
    __shared__ unsigned short sXh[64 * PITCH];
    __shared__ unsigned short sXl[ABF16 ? 1 : 64 * PITCH];

    const int tid  = threadIdx.x;
    const int tile = blockIdx.x;

    #pragma unroll
    for (int rg = 0; rg < 2; ++rg) {
        const int row = rg * 32 + (tid >> 3);
        const int c0  = (tid & 7) * 16;
        const int n   = tile * 64 + row;
        const int base = row * PITCH + c0;
        if constexpr (ABF16) {
            const unsigned short* xin = (const unsigned short*)xin_;
            short8 a = {0,0,0,0,0,0,0,0}, b = a;
            if (n < N) {
                const short8* p = (const short8*)(xin + (size_t)n * FF + c0);
                a = p[0]; b = p[1];
            }
            *(short8*)&sXh[base]     = a;
            *(short8*)&sXh[base + 8] = b;
        } else {
            const float* xin = (const float*)xin_;
            float v[16];
            if (n < N) {
                const float4* p = (const float4*)(xin + (size_t)n * FF + c0);
                #pragma unroll
                for (int i = 0; i < 4; ++i) {
                    float4 q = p[i];
                    v[4*i] = q.x; v[4*i+1] = q.y; v[4*i+2] = q.z; v[4*i+3] = q.w;
                }
            } else {
                #pragma unroll
                for (int i = 0; i < 16; ++i) v[i] = 0.f;
            }
            if constexpr (PRE == 1) {
                float ss = 0.f;
                #pragma unroll
                for (int i = 0; i < 16; ++i) ss = fmaf(v[i], v[i], ss);
                ss += __shfl_xor(ss, 1);
                ss += __shfl_xor(ss, 2);
                ss += __shfl_xor(ss, 4);
                float scl = 1.0f / fmaxf(sqrtf(ss), 1e-12f);
                #pragma unroll
                for (int i = 0; i < 16; ++i) v[i] *= scl;
            }
            union { unsigned short u[8]; short8 s; } h0, h1, l0, l1;
            #pragma unroll
            for (int i = 0; i < 8; ++i) {
                unsigned short ha = bf16_rne(v[i]);
                unsigned short hb = bf16_rne(v[8 + i]);
                h0.u[i] = ha; h1.u[i] = hb;
                l0.u[i] = bf16_rne(v[i]     - bf16_to_f32(ha));
                l1.u[i] = bf16_rne(v[8 + i] - bf16_to_f32(hb));
            }
            *(short8*)&sXh[base]     = h0.s;
            *(short8*)&sXh[base + 8] = h1.s;
            *(short8*)&sXl[base]     = l0.s;
            *(short8*)&sXl[base + 8] = l1.s;
        }
    }
    __syncthreads();

    const int lane = tid & 63, wave = tid >> 6;
    const int quad = lane >> 4, l16 = lane & 15;
    constexpr int CT = (OUT == 128) ? 2 : 1;

    short8 Bh[CT][4], Bl[CT][4];
    #pragma unroll
    for (int c = 0; c < CT; ++c) {
        const int jt = (OUT == 128) ? (2 * wave + c) : wave;
        #pragma unroll
        for (int t = 0; t < 4; ++t) {
            const size_t o = ((size_t)(jt * 4 + t) * 64 + lane) * 8;
            Bh[c][t] = *(const short8*)&Wh[o];
            Bl[c][t] = *(const short8*)&Wl[o];
        }
    }

    f32x4 acc[4][CT];
    #pragma unroll
    for (int r = 0; r < 4; ++r)
        #pragma unroll
        for (int c = 0; c < CT; ++c) {
            f32x4 z = {0.f, 0.f, 0.f, 0.f};
            acc[r][c] = z;
        }

    #pragma unroll
    for (int t = 0; t < 4; ++t) {
        short8 Ah[4], Al[4];
        #pragma unroll
        for (int r = 0; r < 4; ++r) {
            const int off = (r * 16 + l16) * PITCH + t * 32 + quad * 8;
            Ah[r] = *(const short8*)&sXh[off];
            if constexpr (!ABF16) Al[r] = *(const short8*)&sXl[off];
        }
        #pragma unroll
        for (int c = 0; c < CT; ++c)
            #pragma unroll
            for (int r = 0; r < 4; ++r) {
                acc[r][c] = __builtin_amdgcn_mfma_f32_16x16x32_bf16(Ah[r], Bh[c][t], acc[r][c], 0, 0, 0);
                if constexpr (!ABF16)
                    acc[r][c] = __builtin_amdgcn_mfma_f32_16x16x32_bf16(Al[r], Bh[c][t], acc[r][c], 0, 0, 0);
                acc[r][c] = __builtin_amdgcn_mfma_f32_16x16x32_bf16(Ah[r], Bl[c][t], acc[r][c], 0, 0, 0);
            }
    }

    #pragma unroll
    for (int c = 0; c < CT; ++c) {
        const int jt = (OUT == 128) ? (2 * wave + c) : wave;
        const int j = jt * 16 + l16;
        const float bj = bias[j];
        #pragma unroll
        for (int r = 0; r < 4; ++r) {
            #pragma unroll
            for (int g = 0; g < 4; ++g) {
                const int n = tile * 64 + r * 16 + quad * 4 + g;
                if (n < N) {
                    float val = acc[r][c][g] + bj;
                    if constexpr (ADD) val += addsrc[(size_t)n * OUT + j];
                    if constexpr (RELU) val = fmaxf(val, 0.f);
                    if constexpr (OUTBF16)
                        ((unsigned short*)out_)[(size_t)n * OUT + j] = bf16_rne(val);
                    else
                        ((float*)out_)[(size_t)n * OUT + j] = val;
                    if constexpr (OUTSQ)
                        hsq_out[(size_t)n * OUT + j] = bf16_rne(val * val);
                }
            }
        }
    }
}

// ---------------------------------------------------------------------------
// Fused fc1+fc2: out[n][j] = act( h[n]@W1[j] + agg[n]@W2[j] + b1[j]+b2[j] )
// h bf16 (exact, 2-term vs W1 hi/lo); agg bf16 hi-plane only (2-term vs W2
// hi/lo; agg's bf16 rounding error ~2^-9 rel is far under threshold).
// Staging is pure short8 copies. 4 MFMA terms total.
// ---------------------------------------------------------------------------
template<int OUT, int RELU>
__global__ __launch_bounds__(256, 2)
void mm2_mfma(const unsigned short* __restrict__ hin,
              const unsigned short* __restrict__ aggh,
              const unsigned short* __restrict__ W1h, const unsigned short* __restrict__ W1l,
              const unsigned short* __restrict__ W2h, const unsigned short* __restrict__ W2l,
              const float* __restrict__ b1, const float* __restrict__ b2,
              float* __restrict__ out_, int N)
{
    constexpr int PITCH = 136;
    __shared__ unsigned short sH [64 * PITCH];
    __shared__ unsigned short sAh[64 * PITCH];

    const int tid  = threadIdx.x;
    const int tile = blockIdx.x;

    #pragma unroll
    for (int rg = 0; rg < 2; ++rg) {
        const int row = rg * 32 + (tid >> 3);
        const int c0  = (tid & 7) * 16;
        const int n   = tile * 64 + row;
        const int base = row * PITCH + c0;
        short8 z = {0,0,0,0,0,0,0,0};
        short8 a = z, b = z, c = z, d = z;
        if (n < N) {
            const short8* ph = (const short8*)(hin  + (size_t)n * FF + c0);
            const short8* pa = (const short8*)(aggh + (size_t)n * FF + c0);
            a = ph[0]; b = ph[1];
            c = pa[0]; d = pa[1];
        }
        *(short8*)&sH [base]     = a;
        *(short8*)&sH [base + 8] = b;
        *(short8*)&sAh[base]     = c;
        *(short8*)&sAh[base + 8] = d;
    }
    __syncthreads();

    const int lane = tid & 63, wave = tid >> 6;
    const int quad = lane >> 4, l16 = lane & 15;
    constexpr int CT = (OUT == 128) ? 2 : 1;

    short8 B1hf[CT][4], B1lf[CT][4], B2hf[CT][4], B2lf[CT][4];
    #pragma unroll
    for (int c = 0; c < CT; ++c) {
        const int jt = (OUT == 128) ? (2 * wave + c) : wave;
        #pragma unroll
        for (int t = 0; t < 4; ++t) {
            const size_t o = ((size_t)(jt * 4 + t) * 64 + lane) * 8;
            B1hf[c][t] = *(const short8*)&W1h[o];
            B1lf[c][t] = *(const short8*)&W1l[o];
            B2hf[c][t] = *(const short8*)&W2h[o];
            B2lf[c][t] = *(const short8*)&W2l[o];
        }
    }

    f32x4 acc[4][CT];
    #pragma unroll
    for (int r = 0; r < 4; ++r)
        #pragma unroll
        for (int c = 0; c < CT; ++c) {
            f32x4 z = {0.f, 0.f, 0.f, 0.f};
            acc[r][c] = z;
        }

    #pragma unroll
    for (int t = 0; t < 4; ++t) {
        short8 Hf[4], AH[4];
        #pragma unroll
        for (int r = 0; r < 4; ++r) {
            const int off = (r * 16 + l16) * PITCH + t * 32 + quad * 8;
            Hf[r] = *(const short8*)&sH[off];
            AH[r] = *(const short8*)&sAh[off];
        }
        #pragma unroll
        for (int c = 0; c < CT; ++c)
            #pragma unroll
            for (int r = 0; r < 4; ++r) {
                acc[r][c] = __builtin_amdgcn_mfma_f32_16x16x32_bf16(Hf[r], B1hf[c][t], acc[r][c], 0, 0, 0);
                acc[r][c] = __builtin_amdgcn_mfma_f32_16x16x32_bf16(Hf[r], B1lf[c][t], acc[r][c], 0, 0, 0);
                acc[r][c] = __builtin_amdgcn_mfma_f32_16x16x32_bf16(AH[r], B2hf[c][t], acc[r][c], 0, 0, 0);
                acc[r][c] = __builtin_amdgcn_mfma_f32_16x16x32_bf16(AH[r], B2lf[c][t], acc[r][c], 0, 0, 0);
            }
    }

    #pragma unroll
    for (int c = 0; c < CT; ++c) {
        const int jt = (OUT == 128) ? (2 * wave + c) : wave;
        const int j = jt * 16 + l16;
        const float bj = b1[j] + b2[j];
        #pragma unroll
        for (int r = 0; r < 4; ++r) {
            #pragma unroll
            for (int g = 0; g < 4; ++g) {
                const int n = tile * 64 + r * 16 + quad * 4 + g;
                if (n < N) {
                    float val = acc[r][c][g] + bj;
                    if constexpr (RELU) val = fmaxf(val, 0.f);
                    out_[(size_t)n * OUT + j] = val;
                }
            }
        }
    }
}

// ---------------------------------------------------------------------------
// Weight prep: fp32 [OUT][128] -> fragment-major bf16 hi/lo planes.
// Block 0 also zeroes bucket_cnt (replaces a memset dispatch).
// ---------------------------------------------------------------------------
struct WPack {
    const float* src[6];
    unsigned short* hi[6];
    unsigned short* lo[6];
    int n[6];
};

__global__ __launch_bounds__(256)
void wprep_kernel(WPack p, int* __restrict__ bucket_cnt)
{
    if (blockIdx.x == 0) bucket_cnt[threadIdx.x] = 0;
    int id = blockIdx.x * 256 + threadIdx.x;
    #pragma unroll
    for (int i = 0; i < 6; ++i) {
        if (id < p.n[i]) {
            float f = p.src[i][id];
            unsigned short h = bf16_rne(f);
            const int j = id >> 7, k = id & 127;
            const int jt = j >> 4, l16 = j & 15;
            const int t = k >> 5, quad = (k >> 3) & 3, j8 = k & 7;
            const size_t o = ((size_t)((jt * 4 + t) * 4 + quad) * 16 + l16) * 8 + j8;
            p.hi[i][o] = h;
            p.lo[i][o] = bf16_rne(f - bf16_to_f32(h));
            return;
        }
        id -= p.n[i];
    }
}

// ---------------------------------------------------------------------------
// Pass A: bucket partition. bucket = dst >> 8. Edges staged in LDS grouped by
// bucket, then written as coalesced runs into over-provisioned bucket regions.
// Entry: {x = src | (dst<<16), y = val fp32}.   (requires N <= 65536)
// ---------------------------------------------------------------------------
__global__ __launch_bounds__(256)
void partA_kernel(const int* __restrict__ src, const int* __restrict__ dst,
                  const float* __restrict__ val, int* __restrict__ bucket_cnt,
                  int2* __restrict__ ebuf, int E)
{
    __shared__ int cnt[256], sc[256], excl[256], cur[256], gbase[256];
    __shared__ int2 staged[CHUNK];
    const int t = threadIdx.x;
    const int e0 = blockIdx.x * CHUNK;
    const int n  = min(CHUNK, E - e0);

    cnt[t] = 0;
    __syncthreads();
    for (int i = t; i < n; i += 256)
        atomicAdd(&cnt[((unsigned)dst[e0 + i]) >> 8], 1);
    __syncthreads();

    sc[t] = cnt[t];
    __syncthreads();
    #pragma unroll
    for (int off = 1; off < 256; off <<= 1) {
        int v = (t >= off) ? sc[t - off] : 0;
        __syncthreads();
        sc[t] += v;
        __syncthreads();
    }
    excl[t] = sc[t] - cnt[t];
    cur[t]  = excl[t];
    if (cnt[t] > 0) gbase[t] = atomicAdd(&bucket_cnt[t], cnt[t]);
    __syncthreads();

    for (int i = t; i < n; i += 256) {
        int d = dst[e0 + i];
        int s = src[e0 + i];
        float v = val[e0 + i];
        int b = ((unsigned)d) >> 8;
        int slot = atomicAdd(&cur[b], 1);
        staged[slot] = make_int2((s & 0xffff) | (d << 16), __float_as_int(v));
    }
    __syncthreads();

    for (int p = t; p < n; p += 256) {
        int2 ent = staged[p];
        int b = ((unsigned)ent.x) >> 24;
        int gpos = gbase[b] + (p - excl[b]);
        ebuf[(size_t)b * BCAP + gpos] = ent;
    }
}

// ---------------------------------------------------------------------------
// Pass B: per-bucket fine sort. One block per bucket. Computes per-dst offsets,
// then scatters final edata {src, val} into the bucket's compact region.
// ---------------------------------------------------------------------------
__global__ __launch_bounds__(256)
void partB_kernel(const int* __restrict__ bucket_cnt, const int2* __restrict__ ebuf,
                  int* __restrict__ offsets, int2* __restrict__ edata,
                  int N, int E, int nbuck)
{
    __shared__ int pre[256], hist[256], sc[256], excl[256], cur[256];
    const int t = threadIdx.x;
    const int b = blockIdx.x;

    pre[t] = (t < nbuck) ? bucket_cnt[t] : 0;
    __syncthreads();
    #pragma unroll
    for (int off = 1; off < 256; off <<= 1) {
        int v = (t >= off) ? pre[t - off] : 0;
        __syncthreads();
        pre[t] += v;
        __syncthreads();
    }
    const int base = (b == 0) ? 0 : pre[b - 1];
    const int cnt  = pre[b] - base;

    hist[t] = 0;
    __syncthreads();
    const int2* ib = ebuf + (size_t)b * BCAP;
    for (int i = t; i < cnt; i += 256)
        atomicAdd(&hist[(((unsigned)ib[i].x) >> 16) & 255], 1);
    __syncthreads();

    sc[t] = hist[t];
    __syncthreads();
    #pragma unroll
    for (int off = 1; off < 256; off <<= 1) {
        int v = (t >= off) ? sc[t - off] : 0;
        __syncthreads();
        sc[t] += v;
        __syncthreads();
    }
    excl[t] = sc[t] - hist[t];
    cur[t]  = excl[t];

    const int node = b * 256 + t;
    if (node <= N) offsets[node] = base + excl[t];
    __syncthreads();

    for (int i = t; i < cnt; i += 256) {
        int2 ent = ib[i];
        int l = (((unsigned)ent.x) >> 16) & 255;
        int pos = base + atomicAdd(&cur[l], 1);
        edata[pos] = make_int2(ent.x & 0xffff, ent.y);
    }
}

// ---------------------------------------------------------------------------
// CSR aggregation over bf16 hsq: one node per 32-lane group (8 nodes/block);
// lane covers 4 feats (one 8B read). agg = sqrt(sum val*hsq) written as a
// single bf16 hi plane (2^-9 rel rounding — within accuracy budget).
// ---------------------------------------------------------------------------
__device__ __forceinline__ void fma4(float4& a, float v, uint2 u) {
    a.x = fmaf(v, __uint_as_float(u.x << 16), a.x);
    a.y = fmaf(v, __uint_as_float(u.x & 0xffff0000u), a.y);
    a.z = fmaf(v, __uint_as_float(u.y << 16), a.z);
    a.w = fmaf(v, __uint_as_float(u.y & 0xffff0000u), a.w);
}

__global__ __launch_bounds__(256)
void agg_kernel(const unsigned short* __restrict__ hsq, const int* __restrict__ offsets,
                const int2* __restrict__ edata,
                unsigned short* __restrict__ aggh, int N)
{
    const int w = blockIdx.x * 8 + (threadIdx.x >> 5);
    if (w >= N) return;
    const int l = threadIdx.x & 31;
    const size_t fo = (size_t)(l * 4);
    int e = offsets[w];
    const int end = offsets[w + 1];

    float4 a0 = {0,0,0,0}, a1 = {0,0,0,0}, a2 = {0,0,0,0}, a3 = {0,0,0,0};

    if ((e & 1) && e < end) {
        int2 ed = edata[e];
        uint2 u = *(const uint2*)&hsq[(size_t)ed.x * FF + fo];
        fma4(a0, __int_as_float(ed.y), u);
        ++e;
    }
    for (; e + 3 < end; e += 4) {
        int4 p0 = *(const int4*)&edata[e];
        int4 p1 = *(const int4*)&edata[e + 2];
        uint2 u0 = *(const uint2*)&hsq[(size_t)p0.x * FF + fo];
        uint2 u1 = *(const uint2*)&hsq[(size_t)p0.z * FF + fo];
        uint2 u2 = *(const uint2*)&hsq[(size_t)p1.x * FF + fo];
        uint2 u3 = *(const uint2*)&hsq[(size_t)p1.z * FF + fo];
        fma4(a0, __int_as_float(p0.y), u0);
        fma4(a1, __int_as_float(p0.w), u1);
        fma4(a2, __int_as_float(p1.y), u2);
        fma4(a3, __int_as_float(p1.w), u3);
    }
    if (e + 1 < end) {
        int4 p = *(const int4*)&edata[e];
        uint2 u0 = *(const uint2*)&hsq[(size_t)p.x * FF + fo];
        uint2 u1 = *(const uint2*)&hsq[(size_t)p.z * FF + fo];
        fma4(a0, __int_as_float(p.y), u0);
        fma4(a1, __int_as_float(p.w), u1);
        e += 2;
    }
    if (e < end) {
        int2 ed = edata[e];
        uint2 u = *(const uint2*)&hsq[(size_t)ed.x * FF + fo];
        fma4(a0, __int_as_float(ed.y), u);
    }

    float4 r;
    r.x = sqrtf(a0.x + a1.x + a2.x + a3.x);
    r.y = sqrtf(a0.y + a1.y + a2.y + a3.y);
    r.z = sqrtf(a0.z + a1.z + a2.z + a3.z);
    r.w = sqrtf(a0.w + a1.w + a2.w + a3.w);

    uint2 hv = { (unsigned)bf16_rne(r.x) | ((unsigned)bf16_rne(r.y) << 16),
                 (unsigned)bf16_rne(r.z) | ((unsigned)bf16_rne(r.w) << 16) };
    *(uint2*)&aggh[(size_t)w * FF + fo] = hv;
}

// ---------------------------------------------------------------------------
extern "C" void kernel_launch(void* const* d_in, const int* in_sizes, int n_in,
                              void* d_out, int out_size, void* d_ws, size_t ws_size,
                              hipStream_t stream) {
    const float* x    = (const float*)d_in[0];
    const int*   esrc = (const int*)d_in[1];
    const int*   edst = (const int*)d_in[2];
    const float* eval = (const float*)d_in[3];
    const float* pw0  = (const float*)d_in[4];
    const float* pb0  = (const float*)d_in[5];
    const float* f1w0 = (const float*)d_in[6];
    const float* f1b0 = (const float*)d_in[7];
    const float* f2w0 = (const float*)d_in[8];
    const float* f2b0 = (const float*)d_in[9];
    const float* pw1  = (const float*)d_in[10];
    const float* pb1  = (const float*)d_in[11];
    const float* f1w1 = (const float*)d_in[12];
    const float* f1b1 = (const float*)d_in[13];
    const float* f2w1 = (const float*)d_in[14];
    const float* f2b1 = (const float*)d_in[15];
    float* out = (float*)d_out;

    const int N = in_sizes[0] / FF;     // 50000  (must be <= 65536 for 16-bit packing)
    const int E = in_sizes[1];          // 800000
    const int nbuck = (N + 255) / 256;  // 196

    char* ws = (char*)d_ws;
    const size_t rowsz = (size_t)N * FF * sizeof(float);          // 25.6 MB
    const size_t A = 256;
    size_t off = 0;
    unsigned short* h    = (unsigned short*)(ws + off); off += (rowsz / 2 + A - 1) / A * A;
    unsigned short* hsq  = (unsigned short*)(ws + off); off += (rowsz / 2 + A - 1) / A * A;
    unsigned short* aggh = (unsigned short*)(ws + off); off += (rowsz / 2 + A - 1) / A * A;
    float* x1  = (float*)(ws + off); off += rowsz;
    int* offsets = (int*)(ws + off); off += ((size_t)(N + 1) * 4 + A - 1) / A * A;
    int* bucket_cnt = (int*)(ws + off); off += (size_t)256 * 4;
    int2* ebuf  = (int2*)(ws + off); off += (size_t)nbuck * BCAP * 8;   // 12.8 MB
    int2* edata = (int2*)(ws + off); off += (size_t)E * 8;
    const int wsz[6] = {128 * FF, 128 * FF, 128 * FF, 128 * FF, 64 * FF, 64 * FF};
    unsigned short* whi[6];
    unsigned short* wlo[6];
    for (int i = 0; i < 6; ++i) {
        whi[i] = (unsigned short*)(ws + off); off += (size_t)wsz[i] * 2;
        wlo[i] = (unsigned short*)(ws + off); off += (size_t)wsz[i] * 2;
    }

    WPack pack;
    const float* wsrc[6] = {pw0, f1w0, f2w0, pw1, f1w1, f2w1};
    int wtotal = 0;
    for (int i = 0; i < 6; ++i) {
        pack.src[i] = wsrc[i]; pack.hi[i] = whi[i]; pack.lo[i] = wlo[i]; pack.n[i] = wsz[i];
        wtotal += wsz[i];
    }

    const int ntiles     = (N + 63) / 64;
    const int nodeblocks = (N + 7) / 8;
    dim3 B(256);

    // ---- weight prep (fragment-major bf16 split) + bucket_cnt zero ----
    wprep_kernel<<<(wtotal + 255) / 256, B, 0, stream>>>(pack, bucket_cnt);

    // ---- edge partition + dst-sort ----
    partA_kernel<<<(E + CHUNK - 1) / CHUNK, B, 0, stream>>>(esrc, edst, eval, bucket_cnt, ebuf, E);
    partB_kernel<<<nbuck, B, 0, stream>>>(bucket_cnt, ebuf, offsets, edata, N, E, nbuck);

    // ---- layer 0 (128 -> 128, relu) ----
    mm_mfma<128, 1, 0, 1, 0, 1, 1><<<ntiles, B, 0, stream>>>(x, whi[0], wlo[0], pb0, nullptr, h, hsq, N);
    agg_kernel<<<nodeblocks, B, 0, stream>>>(hsq, offsets, edata, aggh, N);
    mm2_mfma<128, 1><<<ntiles, B, 0, stream>>>(h, aggh, whi[1], wlo[1], whi[2], wlo[2], f1b0, f2b0, x1, N);

    // ---- layer 1 (128 -> 64, no act) ----
    mm_mfma<128, 1, 0, 1, 0, 1, 1><<<ntiles, B, 0, stream>>>(x1, whi[3], wlo[3], pb1, nullptr, h, hsq, N);
    agg_kernel<<<nodeblocks, B, 0, stream>>>(hsq, offsets, edata, aggh, N);
    mm2_mfma<64, 0><<<ntiles, B, 0, stream>>>(h, aggh, whi[4], wlo[4], whi[5], wlo[5], f1b1, f2b1, out, N);
}

// Round 11
// 248.569 us; speedup vs baseline: 1.1033x; 1.0348x over previous
//
#include <hip/hip_runtime.h>

#define FF 128
#define BCAP 8192       // per-bucket region capacity (avg ~4081 for seeded input)
#define CHUNK 4096      // edges per partA block

typedef __attribute__((ext_vector_type(8))) short short8;
typedef __attribute__((ext_vector_type(4))) float f32x4;

__device__ __forceinline__ unsigned short bf16_rne(float f) {
    unsigned u = __float_as_uint(f);
    u += 0x7fffu + ((u >> 16) & 1u);
    return (unsigned short)(u >> 16);
}
__device__ __forceinline__ float bf16_to_f32(unsigned short h) {
    return __uint_as_float(((unsigned)h) << 16);
}

// ---------------------------------------------------------------------------
// Pool matmul with FOLDED L2-normalization:
//   h[n][j] = relu( dot(x[n], W[j]) * (1/||x[n]||) + b[j] )
// (normalization is linear -> scale applied in epilogue, so A is a SINGLE
//  bf16 plane: 2-term MFMA vs W hi/lo, one LDS plane, light staging.)
// Writes h (bf16) and hsq = bf16(h^2). 64-node tile, 4 waves, 2 col-tiles/wave.
// ABF16: input already bf16 (x1) vs fp32 (x, rounded once to bf16).
// ---------------------------------------------------------------------------
template<int ABF16>
__global__ __launch_bounds__(256, 2)
void pool_mfma(const void* __restrict__ xin_,
               const unsigned short* __restrict__ Wh, const unsigned short* __restrict__ Wl,
               const float* __restrict__ bias,
               unsigned short* __restrict__ hout, unsigned short* __restrict__ hsqout, int N)
{
    constexpr int PITCH = 136;
    __shared__ unsigned short sX[64 * PITCH];
    __shared__ float sNorm[64];

    const int tid  = threadIdx.x;
    const int tile = blockIdx.x;

    // ---- stage x tile (64 rows x 128) + per-row 1/norm ----
    #pragma unroll
    for (int rg = 0; rg < 2; ++rg) {
        const int row = rg * 32 + (tid >> 3);
        const int c0  = (tid & 7) * 16;
        const int n   = tile * 64 + row;
        const int base = row * PITCH + c0;
        float ss = 0.f;
        if constexpr (ABF16) {
            const unsigned short* xin = (const unsigned short*)xin_;
            union { short8 s; unsigned short u[8]; } a, b;
            short8 z = {0,0,0,0,0,0,0,0};
            a.s = z; b.s = z;
            if (n < N) {
                const short8* p = (const short8*)(xin + (size_t)n * FF + c0);
                a.s = p[0]; b.s = p[1];
            }
            #pragma unroll
            for (int i = 0; i < 8; ++i) {
                float fa = bf16_to_f32(a.u[i]);
                float fb = bf16_to_f32(b.u[i]);
                ss = fmaf(fa, fa, fmaf(fb, fb, ss));
            }
            *(short8*)&sX[base]     = a.s;
            *(short8*)&sX[base + 8] = b.s;
        } else {
            const float* xin = (const float*)xin_;
            float v[16];
            if (n < N) {
                const float4* p = (const float4*)(xin + (size_t)n * FF + c0);
                #pragma unroll
                for (int i = 0; i < 4; ++i) {
                    float4 q = p[i];
                    v[4*i] = q.x; v[4*i+1] = q.y; v[4*i+2] = q.z; v[4*i+3] = q.w;
                }
            } else {
                #pragma unroll
                for (int i = 0; i < 16; ++i) v[i] = 0.f;
            }
            #pragma unroll
            for (int i = 0; i < 16; ++i) ss = fmaf(v[i], v[i], ss);
            union { unsigned short u[8]; short8 s; } h0, h1;
            #pragma unroll
            for (int i = 0; i < 8; ++i) {
                h0.u[i] = bf16_rne(v[i]);
                h1.u[i] = bf16_rne(v[8 + i]);
            }
            *(short8*)&sX[base]     = h0.s;
            *(short8*)&sX[base + 8] = h1.s;
        }
        // reduce ss across the 8 lanes covering this row
        ss += __shfl_xor(ss, 1);
        ss += __shfl_xor(ss, 2);
        ss += __shfl_xor(ss, 4);
        if ((tid & 7) == 0) sNorm[row] = 1.0f / fmaxf(sqrtf(ss), 1e-12f);
    }
    __syncthreads();

    const int lane = tid & 63, wave = tid >> 6;
    const int quad = lane >> 4, l16 = lane & 15;

    // ---- W fragments (coalesced 1KB loads, fragment-major) ----
    short8 Bh[2][4], Bl[2][4];
    #pragma unroll
    for (int c = 0; c < 2; ++c) {
        const int jt = 2 * wave + c;
        #pragma unroll
        for (int t = 0; t < 4; ++t) {
            const size_t o = ((size_t)(jt * 4 + t) * 64 + lane) * 8;
            Bh[c][t] = *(const short8*)&Wh[o];
            Bl[c][t] = *(const short8*)&Wl[o];
        }
    }

    f32x4 acc[4][2];
    #pragma unroll
    for (int r = 0; r < 4; ++r)
        #pragma unroll
        for (int c = 0; c < 2; ++c) {
            f32x4 z = {0.f, 0.f, 0.f, 0.f};
            acc[r][c] = z;
        }

    // ---- K loop: 2-term (A exact bf16) ----
    #pragma unroll
    for (int t = 0; t < 4; ++t) {
        short8 Ah[4];
        #pragma unroll
        for (int r = 0; r < 4; ++r)
            Ah[r] = *(const short8*)&sX[(r * 16 + l16) * PITCH + t * 32 + quad * 8];
        #pragma unroll
        for (int c = 0; c < 2; ++c)
            #pragma unroll
            for (int r = 0; r < 4; ++r) {
                acc[r][c] = __builtin_amdgcn_mfma_f32_16x16x32_bf16(Ah[r], Bh[c][t], acc[r][c], 0, 0, 0);
                acc[r][c] = __builtin_amdgcn_mfma_f32_16x16x32_bf16(Ah[r], Bl[c][t], acc[r][c], 0, 0, 0);
            }
    }

    // ---- epilogue: scale by 1/norm, +bias, relu, write h + hsq ----
    #pragma unroll
    for (int c = 0; c < 2; ++c) {
        const int j = (2 * wave + c) * 16 + l16;
        const float bj = bias[j];
        #pragma unroll
        for (int r = 0; r < 4; ++r) {
            #pragma unroll
            for (int g = 0; g < 4; ++g) {
                const int nl = r * 16 + quad * 4 + g;
                const int n = tile * 64 + nl;
                if (n < N) {
                    float s = sNorm[nl];                       // LDS broadcast
                    float val = fmaf(acc[r][c][g], s, bj);
                    val = fmaxf(val, 0.f);
                    hout  [(size_t)n * FF + j] = bf16_rne(val);
                    hsqout[(size_t)n * FF + j] = bf16_rne(val * val);
                }
            }
        }
    }
}

// ---------------------------------------------------------------------------
// Fused fc1+fc2: out[n][j] = act( h[n]@W1[j] + agg[n]@W2[j] + b1[j]+b2[j] )
// h bf16 (exact, 2-term vs W1 hi/lo); agg bf16 hi-plane (2-term vs W2 hi/lo).
// OUTBF16: write bf16 (x1 for the next layer) vs fp32 (final output).
// ---------------------------------------------------------------------------
template<int OUT, int RELU, int OUTBF16>
__global__ __launch_bounds__(256, 2)
void mm2_mfma(const unsigned short* __restrict__ hin,
              const unsigned short* __restrict__ aggh,
              const unsigned short* __restrict__ W1h, const unsigned short* __restrict__ W1l,
              const unsigned short* __restrict__ W2h, const unsigned short* __restrict__ W2l,
              const float* __restrict__ b1, const float* __restrict__ b2,
              void* __restrict__ out_, int N)
{
    constexpr int PITCH = 136;
    __shared__ unsigned short sH [64 * PITCH];
    __shared__ unsigned short sAh[64 * PITCH];

    const int tid  = threadIdx.x;
    const int tile = blockIdx.x;

    #pragma unroll
    for (int rg = 0; rg < 2; ++rg) {
        const int row = rg * 32 + (tid >> 3);
        const int c0  = (tid & 7) * 16;
        const int n   = tile * 64 + row;
        const int base = row * PITCH + c0;
        short8 z = {0,0,0,0,0,0,0,0};
        short8 a = z, b = z, c = z, d = z;
        if (n < N) {
            const short8* ph = (const short8*)(hin  + (size_t)n * FF + c0);
            const short8* pa = (const short8*)(aggh + (size_t)n * FF + c0);
            a = ph[0]; b = ph[1];
            c = pa[0]; d = pa[1];
        }
        *(short8*)&sH [base]     = a;
        *(short8*)&sH [base + 8] = b;
        *(short8*)&sAh[base]     = c;
        *(short8*)&sAh[base + 8] = d;
    }
    __syncthreads();

    const int lane = tid & 63, wave = tid >> 6;
    const int quad = lane >> 4, l16 = lane & 15;
    constexpr int CT = (OUT == 128) ? 2 : 1;

    short8 B1hf[CT][4], B1lf[CT][4], B2hf[CT][4], B2lf[CT][4];
    #pragma unroll
    for (int c = 0; c < CT; ++c) {
        const int jt = (OUT == 128) ? (2 * wave + c) : wave;
        #pragma unroll
        for (int t = 0; t < 4; ++t) {
            const size_t o = ((size_t)(jt * 4 + t) * 64 + lane) * 8;
            B1hf[c][t] = *(const short8*)&W1h[o];
            B1lf[c][t] = *(const short8*)&W1l[o];
            B2hf[c][t] = *(const short8*)&W2h[o];
            B2lf[c][t] = *(const short8*)&W2l[o];
        }
    }

    f32x4 acc[4][CT];
    #pragma unroll
    for (int r = 0; r < 4; ++r)
        #pragma unroll
        for (int c = 0; c < CT; ++c) {
            f32x4 z = {0.f, 0.f, 0.f, 0.f};
            acc[r][c] = z;
        }

    #pragma unroll
    for (int t = 0; t < 4; ++t) {
        short8 Hf[4], AH[4];
        #pragma unroll
        for (int r = 0; r < 4; ++r) {
            const int off = (r * 16 + l16) * PITCH + t * 32 + quad * 8;
            Hf[r] = *(const short8*)&sH[off];
            AH[r] = *(const short8*)&sAh[off];
        }
        #pragma unroll
        for (int c = 0; c < CT; ++c)
            #pragma unroll
            for (int r = 0; r < 4; ++r) {
                acc[r][c] = __builtin_amdgcn_mfma_f32_16x16x32_bf16(Hf[r], B1hf[c][t], acc[r][c], 0, 0, 0);
                acc[r][c] = __builtin_amdgcn_mfma_f32_16x16x32_bf16(Hf[r], B1lf[c][t], acc[r][c], 0, 0, 0);
                acc[r][c] = __builtin_amdgcn_mfma_f32_16x16x32_bf16(AH[r], B2hf[c][t], acc[r][c], 0, 0, 0);
                acc[r][c] = __builtin_amdgcn_mfma_f32_16x16x32_bf16(AH[r], B2lf[c][t], acc[r][c], 0, 0, 0);
            }
    }

    #pragma unroll
    for (int c = 0; c < CT; ++c) {
        const int jt = (OUT == 128) ? (2 * wave + c) : wave;
        const int j = jt * 16 + l16;
        const float bj = b1[j] + b2[j];
        #pragma unroll
        for (int r = 0; r < 4; ++r) {
            #pragma unroll
            for (int g = 0; g < 4; ++g) {
                const int n = tile * 64 + r * 16 + quad * 4 + g;
                if (n < N) {
                    float val = acc[r][c][g] + bj;
                    if constexpr (RELU) val = fmaxf(val, 0.f);
                    if constexpr (OUTBF16)
                        ((unsigned short*)out_)[(size_t)n * OUT + j] = bf16_rne(val);
                    else
                        ((float*)out_)[(size_t)n * OUT + j] = val;
                }
            }
        }
    }
}

// ---------------------------------------------------------------------------
// Weight prep: fp32 [OUT][128] -> fragment-major bf16 hi/lo planes.
// Block 0 also zeroes bucket_cnt (replaces a memset dispatch).
// ---------------------------------------------------------------------------
struct WPack {
    const float* src[6];
    unsigned short* hi[6];
    unsigned short* lo[6];
    int n[6];
};

__global__ __launch_bounds__(256)
void wprep_kernel(WPack p, int* __restrict__ bucket_cnt)
{
    if (blockIdx.x == 0) bucket_cnt[threadIdx.x] = 0;
    int id = blockIdx.x * 256 + threadIdx.x;
    #pragma unroll
    for (int i = 0; i < 6; ++i) {
        if (id < p.n[i]) {
            float f = p.src[i][id];
            unsigned short h = bf16_rne(f);
            const int j = id >> 7, k = id & 127;
            const int jt = j >> 4, l16 = j & 15;
            const int t = k >> 5, quad = (k >> 3) & 3, j8 = k & 7;
            const size_t o = ((size_t)((jt * 4 + t) * 4 + quad) * 16 + l16) * 8 + j8;
            p.hi[i][o] = h;
            p.lo[i][o] = bf16_rne(f - bf16_to_f32(h));
            return;
        }
        id -= p.n[i];
    }
}

// ---------------------------------------------------------------------------
// Pass A: bucket partition. bucket = dst >> 8. Edges staged in LDS grouped by
// bucket, then written as coalesced runs into over-provisioned bucket regions.
// Entry: {x = src | (dst<<16), y = val fp32}.   (requires N <= 65536)
// ---------------------------------------------------------------------------
__global__ __launch_bounds__(256)
void partA_kernel(const int* __restrict__ src, const int* __restrict__ dst,
                  const float* __restrict__ val, int* __restrict__ bucket_cnt,
                  int2* __restrict__ ebuf, int E)
{
    __shared__ int cnt[256], sc[256], excl[256], cur[256], gbase[256];
    __shared__ int2 staged[CHUNK];
    const int t = threadIdx.x;
    const int e0 = blockIdx.x * CHUNK;
    const int n  = min(CHUNK, E - e0);

    cnt[t] = 0;
    __syncthreads();
    for (int i = t; i < n; i += 256)
        atomicAdd(&cnt[((unsigned)dst[e0 + i]) >> 8], 1);
    __syncthreads();

    sc[t] = cnt[t];
    __syncthreads();
    #pragma unroll
    for (int off = 1; off < 256; off <<= 1) {
        int v = (t >= off) ? sc[t - off] : 0;
        __syncthreads();
        sc[t] += v;
        __syncthreads();
    }
    excl[t] = sc[t] - cnt[t];
    cur[t]  = excl[t];
    if (cnt[t] > 0) gbase[t] = atomicAdd(&bucket_cnt[t], cnt[t]);
    __syncthreads();

    for (int i = t; i < n; i += 256) {
        int d = dst[e0 + i];
        int s = src[e0 + i];
        float v = val[e0 + i];
        int b = ((unsigned)d) >> 8;
        int slot = atomicAdd(&cur[b], 1);
        staged[slot] = make_int2((s & 0xffff) | (d << 16), __float_as_int(v));
    }
    __syncthreads();

    for (int p = t; p < n; p += 256) {
        int2 ent = staged[p];
        int b = ((unsigned)ent.x) >> 24;
        int gpos = gbase[b] + (p - excl[b]);
        ebuf[(size_t)b * BCAP + gpos] = ent;
    }
}

// ---------------------------------------------------------------------------
// Pass B: per-bucket fine sort. One block per bucket. Computes per-dst offsets,
// then scatters final edata {src, val} into the bucket's compact region.
// ---------------------------------------------------------------------------
__global__ __launch_bounds__(256)
void partB_kernel(const int* __restrict__ bucket_cnt, const int2* __restrict__ ebuf,
                  int* __restrict__ offsets, int2* __restrict__ edata,
                  int N, int E, int nbuck)
{
    __shared__ int pre[256], hist[256], sc[256], excl[256], cur[256];
    const int t = threadIdx.x;
    const int b = blockIdx.x;

    pre[t] = (t < nbuck) ? bucket_cnt[t] : 0;
    __syncthreads();
    #pragma unroll
    for (int off = 1; off < 256; off <<= 1) {
        int v = (t >= off) ? pre[t - off] : 0;
        __syncthreads();
        pre[t] += v;
        __syncthreads();
    }
    const int base = (b == 0) ? 0 : pre[b - 1];
    const int cnt  = pre[b] - base;

    hist[t] = 0;
    __syncthreads();
    const int2* ib = ebuf + (size_t)b * BCAP;
    for (int i = t; i < cnt; i += 256)
        atomicAdd(&hist[(((unsigned)ib[i].x) >> 16) & 255], 1);
    __syncthreads();

    sc[t] = hist[t];
    __syncthreads();
    #pragma unroll
    for (int off = 1; off < 256; off <<= 1) {
        int v = (t >= off) ? sc[t - off] : 0;
        __syncthreads();
        sc[t] += v;
        __syncthreads();
    }
    excl[t] = sc[t] - hist[t];
    cur[t]  = excl[t];

    const int node = b * 256 + t;
    if (node <= N) offsets[node] = base + excl[t];
    __syncthreads();

    for (int i = t; i < cnt; i += 256) {
        int2 ent = ib[i];
        int l = (((unsigned)ent.x) >> 16) & 255;
        int pos = base + atomicAdd(&cur[l], 1);
        edata[pos] = make_int2(ent.x & 0xffff, ent.y);
    }
}

// ---------------------------------------------------------------------------
// CSR aggregation over bf16 hsq: one node per 32-lane group (8 nodes/block);
// lane covers 4 feats (one 8B read). agg = sqrt(sum val*hsq) written as a
// single bf16 hi plane.
// ---------------------------------------------------------------------------
__device__ __forceinline__ void fma4(float4& a, float v, uint2 u) {
    a.x = fmaf(v, __uint_as_float(u.x << 16), a.x);
    a.y = fmaf(v, __uint_as_float(u.x & 0xffff0000u), a.y);
    a.z = fmaf(v, __uint_as_float(u.y << 16), a.z);
    a.w = fmaf(v, __uint_as_float(u.y & 0xffff0000u), a.w);
}

__global__ __launch_bounds__(256)
void agg_kernel(const unsigned short* __restrict__ hsq, const int* __restrict__ offsets,
                const int2* __restrict__ edata,
                unsigned short* __restrict__ aggh, int N)
{
    const int w = blockIdx.x * 8 + (threadIdx.x >> 5);
    if (w >= N) return;
    const int l = threadIdx.x & 31;
    const size_t fo = (size_t)(l * 4);
    int e = offsets[w];
    const int end = offsets[w + 1];

    float4 a0 = {0,0,0,0}, a1 = {0,0,0,0}, a2 = {0,0,0,0}, a3 = {0,0,0,0};

    if ((e & 1) && e < end) {
        int2 ed = edata[e];
        uint2 u = *(const uint2*)&hsq[(size_t)ed.x * FF + fo];
        fma4(a0, __int_as_float(ed.y), u);
        ++e;
    }
    for (; e + 3 < end; e += 4) {
        int4 p0 = *(const int4*)&edata[e];
        int4 p1 = *(const int4*)&edata[e + 2];
        uint2 u0 = *(const uint2*)&hsq[(size_t)p0.x * FF + fo];
        uint2 u1 = *(const uint2*)&hsq[(size_t)p0.z * FF + fo];
        uint2 u2 = *(const uint2*)&hsq[(size_t)p1.x * FF + fo];
        uint2 u3 = *(const uint2*)&hsq[(size_t)p1.z * FF + fo];
        fma4(a0, __int_as_float(p0.y), u0);
        fma4(a1, __int_as_float(p0.w), u1);
        fma4(a2, __int_as_float(p1.y), u2);
        fma4(a3, __int_as_float(p1.w), u3);
    }
    if (e + 1 < end) {
        int4 p = *(const int4*)&edata[e];
        uint2 u0 = *(const uint2*)&hsq[(size_t)p.x * FF + fo];
        uint2 u1 = *(const uint2*)&hsq[(size_t)p.z * FF + fo];
        fma4(a0, __int_as_float(p.y), u0);
        fma4(a1, __int_as_float(p.w), u1);
        e += 2;
    }
    if (e < end) {
        int2 ed = edata[e];
        uint2 u = *(const uint2*)&hsq[(size_t)ed.x * FF + fo];
        fma4(a0, __int_as_float(ed.y), u);
    }

    float4 r;
    r.x = sqrtf(a0.x + a1.x + a2.x + a3.x);
    r.y = sqrtf(a0.y + a1.y + a2.y + a3.y);
    r.z = sqrtf(a0.z + a1.z + a2.z + a3.z);
    r.w = sqrtf(a0.w + a1.w + a2.w + a3.w);

    uint2 hv = { (unsigned)bf16_rne(r.x) | ((unsigned)bf16_rne(r.y) << 16),
                 (unsigned)bf16_rne(r.z) | ((unsigned)bf16_rne(r.w) << 16) };
    *(uint2*)&aggh[(size_t)w * FF + fo] = hv;
}

// ---------------------------------------------------------------------------
extern "C" void kernel_launch(void* const* d_in, const int* in_sizes, int n_in,
                              void* d_out, int out_size, void* d_ws, size_t ws_size,
                              hipStream_t stream) {
    const float* x    = (const float*)d_in[0];
    const int*   esrc = (const int*)d_in[1];
    const int*   edst = (const int*)d_in[2];
    const float* eval = (const float*)d_in[3];
    const float* pw0  = (const float*)d_in[4];
    const float* pb0  = (const float*)d_in[5];
    const float* f1w0 = (const float*)d_in[6];
    const float* f1b0 = (const float*)d_in[7];
    const float* f2w0 = (const float*)d_in[8];
    const float* f2b0 = (const float*)d_in[9];
    const float* pw1  = (const float*)d_in[10];
    const float* pb1  = (const float*)d_in[11];
    const float* f1w1 = (const float*)d_in[12];
    const float* f1b1 = (const float*)d_in[13];
    const float* f2w1 = (const float*)d_in[14];
    const float* f2b1 = (const float*)d_in[15];
    float* out = (float*)d_out;

    const int N = in_sizes[0] / FF;     // 50000  (must be <= 65536 for 16-bit packing)
    const int E = in_sizes[1];          // 800000
    const int nbuck = (N + 255) / 256;  // 196

    char* ws = (char*)d_ws;
    const size_t planesz = (size_t)N * FF * 2;                    // 12.8 MB bf16 plane
    const size_t A = 256;
    size_t off = 0;
    unsigned short* h    = (unsigned short*)(ws + off); off += (planesz + A - 1) / A * A;
    unsigned short* hsq  = (unsigned short*)(ws + off); off += (planesz + A - 1) / A * A;
    unsigned short* aggh = (unsigned short*)(ws + off); off += (planesz + A - 1) / A * A;
    unsigned short* x1   = (unsigned short*)(ws + off); off += (planesz + A - 1) / A * A;
    int* offsets = (int*)(ws + off); off += ((size_t)(N + 1) * 4 + A - 1) / A * A;
    int* bucket_cnt = (int*)(ws + off); off += (size_t)256 * 4;
    int2* ebuf  = (int2*)(ws + off); off += (size_t)nbuck * BCAP * 8;   // 12.8 MB
    int2* edata = (int2*)(ws + off); off += (size_t)E * 8;
    const int wsz[6] = {128 * FF, 128 * FF, 128 * FF, 128 * FF, 64 * FF, 64 * FF};
    unsigned short* whi[6];
    unsigned short* wlo[6];
    for (int i = 0; i < 6; ++i) {
        whi[i] = (unsigned short*)(ws + off); off += (size_t)wsz[i] * 2;
        wlo[i] = (unsigned short*)(ws + off); off += (size_t)wsz[i] * 2;
    }

    WPack pack;
    const float* wsrc[6] = {pw0, f1w0, f2w0, pw1, f1w1, f2w1};
    int wtotal = 0;
    for (int i = 0; i < 6; ++i) {
        pack.src[i] = wsrc[i]; pack.hi[i] = whi[i]; pack.lo[i] = wlo[i]; pack.n[i] = wsz[i];
        wtotal += wsz[i];
    }

    const int ntiles     = (N + 63) / 64;
    const int nodeblocks = (N + 7) / 8;
    dim3 B(256);

    // ---- weight prep (fragment-major bf16 split) + bucket_cnt zero ----
    wprep_kernel<<<(wtotal + 255) / 256, B, 0, stream>>>(pack, bucket_cnt);

    // ---- edge partition + dst-sort ----
    partA_kernel<<<(E + CHUNK - 1) / CHUNK, B, 0, stream>>>(esrc, edst, eval, bucket_cnt, ebuf, E);
    partB_kernel<<<nbuck, B, 0, stream>>>(bucket_cnt, ebuf, offsets, edata, N, E, nbuck);

    // ---- layer 0 (128 -> 128, relu) ----
    pool_mfma<0><<<ntiles, B, 0, stream>>>(x, whi[0], wlo[0], pb0, h, hsq, N);
    agg_kernel<<<nodeblocks, B, 0, stream>>>(hsq, offsets, edata, aggh, N);
    mm2_mfma<128, 1, 1><<<ntiles, B, 0, stream>>>(h, aggh, whi[1], wlo[1], whi[2], wlo[2], f1b0, f2b0, x1, N);

    // ---- layer 1 (128 -> 64, no act) ----
    pool_mfma<1><<<ntiles, B, 0, stream>>>(x1, whi[3], wlo[3], pb1, h, hsq, N);
    agg_kernel<<<nodeblocks, B, 0, stream>>>(hsq, offsets, edata, aggh, N);
    mm2_mfma<64, 0, 0><<<ntiles, B, 0, stream>>>(h, aggh, whi[4], wlo[4], whi[5], wlo[5], f1b1, f2b1, out, N);
}